// Round 3
// baseline (496.917 us; speedup 1.0000x reference)
//
#include <hip/hip_runtime.h>
#include <hip/hip_bf16.h>

#define NBMOL 2048
#define NL 128
#define ND 256

constexpr float NEG_SLOPE = 0.2f;
constexpr float LN_EPS = 1e-5f;

typedef __attribute__((ext_vector_type(8))) short short8;
typedef __attribute__((ext_vector_type(4))) float f32x4;

__device__ __forceinline__ unsigned short f2bf(float f) {
  unsigned int u = __float_as_uint(f);
  u = (u + 0x7FFFu + ((u >> 16) & 1u)) >> 16;   // RNE
  return (unsigned short)u;
}
// pack two fp32 -> one u32 of 2 bf16 (RNE), hopefully v_cvt_pk_bf16_f32
__device__ __forceinline__ unsigned int pk2(float lo, float hi) {
  __hip_bfloat162 h = __float22bfloat162_rn(make_float2(lo, hi));
  unsigned int u;
  __builtin_memcpy(&u, &h, 4);
  return u;
}

// ---- pre-kernel 1: W2 fp32 -> bf16 MFMA-fragment order --------------------
// g = (ks*16 + nt)*64 + lane ; value = W2[(lane&15)+nt*16][(lane>>4)*8 + ks*32 + j]
__global__ __launch_bounds__(256) void pack_w2_kernel(const float* __restrict__ W2,
                                                      unsigned short* __restrict__ w2f) {
  int g = blockIdx.x * 256 + threadIdx.x;      // 0..8191
  int ks = g >> 10;
  int nt = (g >> 6) & 15;
  int l  = g & 63;
  int row = (l & 15) + nt * 16;
  int kb  = ((l >> 4) << 3) + ks * 32;
  const float* src = W2 + row * 256 + kb;
  unsigned short h[8];
#pragma unroll
  for (int j = 0; j < 8; ++j) h[j] = f2bf(src[j]);
  unsigned short* dst = w2f + (size_t)g * 8;
#pragma unroll
  for (int j = 0; j < 8; ++j) dst[j] = h[j];
}

// ---- pre-kernel 2: q = mol @ W1^T + b1 ------------------------------------
__global__ __launch_bounds__(256) void compute_q_kernel(const float* __restrict__ mol,
                                                        const float* __restrict__ W1,
                                                        const float* __restrict__ b1,
                                                        float* __restrict__ q) {
  __shared__ float mol_s[8][ND];
  const int t = threadIdx.x;
  const int b0 = blockIdx.x * 8;
#pragma unroll
  for (int i = 0; i < 8; ++i) mol_s[i][t] = mol[(size_t)(b0 + i) * ND + t];
  __syncthreads();
  float acc[8];
#pragma unroll
  for (int i = 0; i < 8; ++i) acc[i] = 0.f;
  const float4* wrow = (const float4*)(W1 + (size_t)t * ND);
  for (int k4 = 0; k4 < 64; ++k4) {
    float4 w = wrow[k4];
#pragma unroll
    for (int bb = 0; bb < 8; ++bb) {
      float4 m = *(const float4*)&mol_s[bb][k4 * 4];
      acc[bb] += w.x * m.x + w.y * m.y + w.z * m.z + w.w * m.w;
    }
  }
  float bias = b1[t];
#pragma unroll
  for (int bb = 0; bb < 8; ++bb) q[(size_t)(b0 + bb) * ND + t] = acc[bb] + bias;
}

// ---- main fused kernel: 1 molecule/block, 512 threads, no A staging -------
__global__ __launch_bounds__(512, 4) void fused_kernel(
    const float* __restrict__ atom,      // [B,L,D] fp32
    const float* __restrict__ attend,    // [B,L]
    const float* __restrict__ smask,     // [B,L]
    const float* __restrict__ w_align,   // [D]
    const float* __restrict__ b2,        // [D]
    const float* __restrict__ gamma_,    // [D]
    const float* __restrict__ beta_,     // [D]
    const unsigned short* __restrict__ w2f,  // frag-order bf16 W2
    const float* __restrict__ qbuf,      // [B,D] fp32
    float* __restrict__ out)             // [B,D] fp32
{
  __shared__ float __align__(16) sp_s[4][NL];   // per-wc score partials
  __shared__ float __align__(16) attn_s[NL];
  __shared__ float cw_s[2][ND];                 // ctx partials per wr-half
  __shared__ float red_s[2][4];
  __shared__ float t_s;                         // sum of attn

  const int tid  = threadIdx.x;
  const int lane = tid & 63;
  const int wid  = tid >> 6;
  const int wr   = wid >> 2;     // 0..1 row half of L
  const int wc   = wid & 3;      // 0..3 col quarter of D
  const int b    = blockIdx.x;

  // ---- GEMM: nb0 = A @ W2^T, A-fragments straight from global fp32 ----
  f32x4 acc[4][4];
#pragma unroll
  for (int mm = 0; mm < 4; ++mm)
#pragma unroll
    for (int nn = 0; nn < 4; ++nn) acc[mm][nn] = {0.f, 0.f, 0.f, 0.f};

  const float* abase = atom + (size_t)b * (NL * ND)
                     + (size_t)(wr * 64 + (lane & 15)) * ND + ((lane >> 4) << 3);
  const unsigned short* bbase = w2f + (size_t)((wc * 4) * 64 + lane) * 8;

#pragma unroll
  for (int ks = 0; ks < 8; ++ks) {
    short8 bfr[4];
#pragma unroll
    for (int nn = 0; nn < 4; ++nn)
      bfr[nn] = *(const short8*)(bbase + ((size_t)(ks * 16 + nn) * 64) * 8);
    short8 afr[4];
#pragma unroll
    for (int mm = 0; mm < 4; ++mm) {
      const float* ap = abase + mm * 16 * ND + ks * 32;
      float4 a0 = *(const float4*)ap;
      float4 a1 = *(const float4*)(ap + 4);
      union { unsigned int u[4]; short8 s; } f;
      f.u[0] = pk2(a0.x, a0.y); f.u[1] = pk2(a0.z, a0.w);
      f.u[2] = pk2(a1.x, a1.y); f.u[3] = pk2(a1.z, a1.w);
      afr[mm] = f.s;
    }
#pragma unroll
    for (int mm = 0; mm < 4; ++mm)
#pragma unroll
      for (int nn = 0; nn < 4; ++nn)
        acc[mm][nn] = __builtin_amdgcn_mfma_f32_16x16x32_bf16(
            afr[mm], bfr[nn], acc[mm][nn], 0, 0, 0);
  }

  // ---- scores from accumulators ----
  // acc[mm][nn][r]: row = wr*64+mm*16+(lane>>4)*4+r, col = wc*64+nn*16+(lane&15)
  {
    float qv[4], wv[4], bv[4];
    const float* qrow = qbuf + (size_t)b * ND;
#pragma unroll
    for (int nn = 0; nn < 4; ++nn) {
      int col = wc * 64 + nn * 16 + (lane & 15);
      qv[nn] = qrow[col];
      wv[nn] = w_align[col];
      bv[nn] = b2[col];
    }
#pragma unroll
    for (int mm = 0; mm < 4; ++mm) {
#pragma unroll
      for (int r = 0; r < 4; ++r) {
        float s = 0.f;
#pragma unroll
        for (int nn = 0; nn < 4; ++nn) {
          float t2 = qv[nn] + acc[mm][nn][r] + bv[nn];
          s += (t2 >= 0.f ? t2 : NEG_SLOPE * t2) * wv[nn];
        }
        s += __shfl_xor(s, 1);
        s += __shfl_xor(s, 2);
        s += __shfl_xor(s, 4);
        s += __shfl_xor(s, 8);
        if ((lane & 15) == 0)
          sp_s[wc][wr * 64 + mm * 16 + ((lane >> 4) << 2) + r] = s;
      }
    }
  }
  __syncthreads();

  // ---- softmax over L (wave 0); b_align cancels in softmax ----
  if (wid == 0) {
    float s0 = sp_s[0][lane] + sp_s[1][lane] + sp_s[2][lane] + sp_s[3][lane]
               + smask[(size_t)b * NL + lane];
    int l1 = lane + 64;
    float s1 = sp_s[0][l1] + sp_s[1][l1] + sp_s[2][l1] + sp_s[3][l1]
               + smask[(size_t)b * NL + l1];
    float m = fmaxf(s0, s1);
#pragma unroll
    for (int o = 32; o > 0; o >>= 1) m = fmaxf(m, __shfl_xor(m, o));
    float e0 = expf(s0 - m), e1 = expf(s1 - m);
    float sum = e0 + e1;
#pragma unroll
    for (int o = 32; o > 0; o >>= 1) sum += __shfl_xor(sum, o);
    float inv = 1.f / sum;
    float a0 = e0 * inv * attend[(size_t)b * NL + lane];
    float a1 = e1 * inv * attend[(size_t)b * NL + l1];
    attn_s[lane] = a0;
    attn_s[l1]   = a1;
    float tl = a0 + a1;
#pragma unroll
    for (int o = 32; o > 0; o >>= 1) tl += __shfl_xor(tl, o);
    if (lane == 0) t_s = tl;
  }
  __syncthreads();

  // ---- ctx directly from accumulators: ctx[col] = sum_row attn[row]*acc ----
  {
    float cp[4] = {0.f, 0.f, 0.f, 0.f};
#pragma unroll
    for (int mm = 0; mm < 4; ++mm) {
      f32x4 av = *(const f32x4*)&attn_s[wr * 64 + mm * 16 + ((lane >> 4) << 2)];
#pragma unroll
      for (int r = 0; r < 4; ++r)
#pragma unroll
        for (int nn = 0; nn < 4; ++nn)
          cp[nn] += av[r] * acc[mm][nn][r];
    }
#pragma unroll
    for (int nn = 0; nn < 4; ++nn) {
      cp[nn] += __shfl_xor(cp[nn], 16);
      cp[nn] += __shfl_xor(cp[nn], 32);
    }
    if (lane < 16) {
#pragma unroll
      for (int nn = 0; nn < 4; ++nn)
        cw_s[wr][wc * 64 + nn * 16 + lane] = cp[nn];
    }
  }
  __syncthreads();

  // ---- LayerNorm over D (first 4 waves, tid == col) ----
  if (tid < ND) {
    float v = cw_s[0][tid] + cw_s[1][tid] + t_s * b2[tid];
    float sv = v, sq = v * v;
#pragma unroll
    for (int o = 32; o > 0; o >>= 1) {
      sv += __shfl_xor(sv, o);
      sq += __shfl_xor(sq, o);
    }
    if (lane == 0) { red_s[0][wid] = sv; red_s[1][wid] = sq; }
  }
  __syncthreads();
  if (tid < ND) {
    float v = cw_s[0][tid] + cw_s[1][tid] + t_s * b2[tid];
    float sv = red_s[0][0] + red_s[0][1] + red_s[0][2] + red_s[0][3];
    float sq = red_s[1][0] + red_s[1][1] + red_s[1][2] + red_s[1][3];
    float mu = sv * (1.0f / 256.0f);
    float var = fmaxf(sq * (1.0f / 256.0f) - mu * mu, 0.f);
    out[(size_t)b * ND + tid] =
        (v - mu) * rsqrtf(var + LN_EPS) * gamma_[tid] + beta_[tid];
  }
}

extern "C" void kernel_launch(void* const* d_in, const int* in_sizes, int n_in,
                              void* d_out, int out_size, void* d_ws, size_t ws_size,
                              hipStream_t stream) {
  const float* mol     = (const float*)d_in[0];
  const float* atom    = (const float*)d_in[1];
  const float* attend  = (const float*)d_in[2];
  const float* smask   = (const float*)d_in[3];
  const float* W1      = (const float*)d_in[4];
  const float* b1      = (const float*)d_in[5];
  const float* W2      = (const float*)d_in[6];
  const float* b2      = (const float*)d_in[7];
  const float* w_align = (const float*)d_in[8];
  // d_in[9] = b_align: cancels inside softmax, unused
  const float* gamma_  = (const float*)d_in[10];
  const float* beta_   = (const float*)d_in[11];
  float* out = (float*)d_out;

  float* qbuf = (float*)d_ws;                                        // 2 MB
  unsigned short* w2f = (unsigned short*)((char*)d_ws + (size_t)NBMOL * ND * 4);  // 128 KB

  pack_w2_kernel<<<32, 256, 0, stream>>>(W2, w2f);
  compute_q_kernel<<<256, 256, 0, stream>>>(mol, W1, b1, qbuf);
  fused_kernel<<<NBMOL, 512, 0, stream>>>(atom, attend, smask, w_align,
                                          b2, gamma_, beta_, w2f, qbuf, out);
}